// Round 1
// baseline (192.795 us; speedup 1.0000x reference)
//
#include <hip/hip_runtime.h>
#include <math.h>

#define T_LEN      24000
#define W_LEN      81
#define HALF_W     40
#define NK         21
#define MAXORD     10
#define FS_F       48000.0f
#define C_F        343.0f
#define PI_F       3.14159265358979323846f
#define FOUR_PI_F  12.566370614359172f
#define NEG_SLOPE  0.01f
#define MAXIMG     1600
#define NTHREADS   1024

// LDS layout (bytes):
//   rir:    24000 f32          = 96000   (offset 0, 16B aligned)
//   params: 1600 float4        = 25600   (offset 96000, 16B aligned)
//   hann:   84 f32             = 336
//   simg:   63 f32 (3 axes x 21)
//   h1:30, h2:20, zb:9, in:22, rms:9 (room3,mic3,src3), cnt:1 int
#define SMEM_BYTES (96000 + 25600 + 336 + 252 + 120 + 80 + 36 + 88 + 36 + 16)

__global__ __launch_bounds__(NTHREADS)
void rir_fused_kernel(const float* __restrict__ g_in,
                      const float* __restrict__ W1, const float* __restrict__ b1,
                      const float* __restrict__ W2, const float* __restrict__ b2,
                      const float* __restrict__ W3, const float* __restrict__ b3,
                      float* __restrict__ out_rir, float* __restrict__ out_origin)
{
    extern __shared__ unsigned char smem_raw[];
    float*  rir    = (float*)smem_raw;                    // 24000
    float4* params = (float4*)(rir + T_LEN);              // 1600
    float*  hann   = (float*)(params + MAXIMG);           // 81 (+3 pad)
    float*  simg   = hann + 84;                           // 63
    float*  h1     = simg + 63;                           // 30
    float*  h2     = h1 + 30;                             // 20
    float*  zb     = h2 + 20;                             // 9
    float*  sm_in  = zb + 9;                              // 22
    float*  rms    = sm_in + 22;                          // 9: room[0:3], mic[3:6], src[6:9]
    int*    cnt    = (int*)(rms + 9);

    const int tid = threadIdx.x;
    const int b   = blockIdx.x;

    // ---- init: zero rir, hann table, input row, counter ----
    for (int i = tid; i < T_LEN; i += NTHREADS) rir[i] = 0.0f;
    if (tid < W_LEN) {
        float arg = 2.0f * PI_F * (float)tid / (float)(W_LEN - 1);
        hann[tid] = 0.5f * (1.0f - cosf(arg));
    }
    if (tid < 22) sm_in[tid] = g_in[b * 22 + tid];
    if (tid == 0) *cnt = 0;
    __syncthreads();

    // ---- MLP: 22 -> 30 -> 20 -> 9 ----
    if (tid < 30) {
        float a = b1[tid];
        const float* w = W1 + tid * 22;
        #pragma unroll
        for (int i = 0; i < 22; ++i) a += sm_in[i] * w[i];
        h1[tid] = (a >= 0.0f) ? a : NEG_SLOPE * a;
    }
    __syncthreads();
    if (tid < 20) {
        float a = b2[tid];
        const float* w = W2 + tid * 30;
        #pragma unroll
        for (int i = 0; i < 30; ++i) a += h1[i] * w[i];
        h2[tid] = (a >= 0.0f) ? a : NEG_SLOPE * a;
    }
    __syncthreads();
    if (tid < 9) {
        float a = b3[tid];
        const float* w = W3 + tid * 20;
        #pragma unroll
        for (int i = 0; i < 20; ++i) a += h2[i] * w[i];
        zb[tid] = 1.0f / (1.0f + expf(-a));
    }
    __syncthreads();
    if (tid < 3) {
        float room = zb[tid] * 20.0f;
        rms[tid]     = room;
        rms[3 + tid] = zb[3 + tid] * room;   // mic
        rms[6 + tid] = zb[6 + tid] * room;   // src
    }
    __syncthreads();

    // ---- origin output + per-axis image coordinates ----
    if (tid == 0) {
        float dx = rms[3] - rms[6], dy = rms[4] - rms[7], dz = rms[5] - rms[8];
        float dist = sqrtf(dx * dx + dy * dy + dz * dz);
        out_origin[b] = 40.0f + FS_F * dist / C_F;
    }
    if (tid < 63) {
        int a  = tid / NK;
        int i  = tid - a * NK;
        int kk = i - MAXORD;
        float L = rms[a], s = rms[6 + a];
        // even k: k*L + s ; odd k: (k+1)*L - s   (Python mod semantics: parity of k)
        simg[tid] = ((kk & 1) == 0) ? (float)kk * L + s : (float)(kk + 1) * L - s;
    }
    __syncthreads();

    const float mic0 = rms[3], mic1 = rms[4], mic2 = rms[5];

    // ---- build compact valid-image list ----
    for (int c = tid; c < NK * NK * NK; c += NTHREADS) {
        int kxi = c / (NK * NK);
        int rem = c - kxi * (NK * NK);
        int kyi = rem / NK;
        int kzi = rem - kyi * NK;
        int ax = (kxi >= MAXORD) ? kxi - MAXORD : MAXORD - kxi;
        int ay = (kyi >= MAXORD) ? kyi - MAXORD : MAXORD - kyi;
        int az = (kzi >= MAXORD) ? kzi - MAXORD : MAXORD - kzi;
        int order = ax + ay + az;
        if (order > MAXORD) continue;

        float dx = simg[kxi]          - mic0;
        float dy = simg[NK + kyi]     - mic1;
        float dz = simg[2 * NK + kzi] - mic2;
        float d  = sqrtf(dx * dx + dy * dy + dz * dz);
        float delay = 40.0f + (FS_F * d) / C_F;
        float t0f   = floorf(delay);
        if (t0f - (float)HALF_W >= (float)T_LEN) continue;  // window entirely past T

        float frac = delay - t0f;
        float amp  = powf(0.9f, (float)order) / (FOUR_PI_F * fmaxf(d, 0.001f));
        float sp   = sinf(PI_F * frac);
        int pos = atomicAdd(cnt, 1);
        if (pos < MAXIMG) params[pos] = make_float4(amp, frac, sp, t0f);
    }
    __syncthreads();

    int nimg = *cnt;
    if (nimg > MAXIMG) nimg = MAXIMG;
    int ntask = nimg * W_LEN;

    // ---- scatter 81 windowed-sinc taps per image into LDS rir ----
    for (int task = tid; task < ntask; task += NTHREADS) {
        unsigned img = (unsigned)task / (unsigned)W_LEN;
        int j = task - (int)img * W_LEN;
        float4 p = params[img];                 // amp, frac, sin(pi*frac), t0
        int   n = j - HALF_W;
        float x = (float)n - p.y;
        float sv;
        if (x == 0.0f) {
            sv = 1.0f;                          // sinc(0)
        } else {
            // sin(pi*(n-frac)) = -(-1)^n * sin(pi*frac); n parity == j parity
            float sp = (j & 1) ? p.z : -p.z;
            sv = sp / (PI_F * x);
        }
        float val = p.x * sv * hann[j];
        int idx = (int)p.w + n;                 // t0 >= 40 so idx >= 0 always
        if (idx < T_LEN)
            atomicAdd(&rir[idx], val);
    }
    __syncthreads();

    // ---- coalesced writeback ----
    float4* out4 = (float4*)(out_rir + (size_t)b * T_LEN);
    float4* rir4 = (float4*)rir;
    for (int i = tid; i < T_LEN / 4; i += NTHREADS) out4[i] = rir4[i];
}

extern "C" void kernel_launch(void* const* d_in, const int* in_sizes, int n_in,
                              void* d_out, int out_size, void* d_ws, size_t ws_size,
                              hipStream_t stream) {
    const float* g_in = (const float*)d_in[0];
    const float* W1   = (const float*)d_in[1];
    const float* b1   = (const float*)d_in[2];
    const float* W2   = (const float*)d_in[3];
    const float* b2   = (const float*)d_in[4];
    const float* W3   = (const float*)d_in[5];
    const float* b3   = (const float*)d_in[6];

    const int B = in_sizes[0] / 22;

    float* out_rir    = (float*)d_out;
    float* out_origin = out_rir + (size_t)B * T_LEN;

    // allow >64KB dynamic LDS (gfx950 has 160 KiB/CU)
    (void)hipFuncSetAttribute((const void*)rir_fused_kernel,
                              hipFuncAttributeMaxDynamicSharedMemorySize,
                              SMEM_BYTES);

    rir_fused_kernel<<<B, NTHREADS, SMEM_BYTES, stream>>>(
        g_in, W1, b1, W2, b2, W3, b3, out_rir, out_origin);
}